// Round 1
// baseline (42404.358 us; speedup 1.0000x reference)
//
#include <hip/hip_runtime.h>

#define T_STEPS 8192
#define HID 1024
#define G4 4096
#define NBLK 128    // merged blocks: each handles 8 hidden units for BOTH layers
#define NTHR 512    // 8 waves
#define NSLOT 8     // rotation depth

typedef unsigned int uint32;

// Global comm (memset 0xFF each launch): tagged fp32 h values.
// Slot s = t & 7; tag = (t>>3) & 15 in the 4 low mantissa bits.
// Overwrite safety at depth 8: publishing h_{t+8} requires having gathered
// h_{t+7}, which transitively (all-to-all each step) bounds any block's lag
// at <2 steps — every consumer read slot t at least 6 steps before reuse.
struct Comm {
    uint32 hA[NSLOT][HID];   // layer-0 h
    uint32 hB[NSLOT][HID];   // layer-1 h
};

#define LD_AG  __HIP_MEMORY_SCOPE_AGENT

__device__ inline float sigm(float x) { return 1.0f / (1.0f + __expf(-x)); }
__device__ inline float tanh_f(float x) {
    x = fminf(fmaxf(x, -15.f), 15.f);
    float e = __expf(-2.0f * x);
    return (1.0f - e) / (1.0f + e);
}
__device__ inline uint32 tagf(float f, uint32 tg) {
    union { float f; uint32 u; } a; a.f = f;
    return (a.u & ~15u) | tg;
}

// out[m][perm(n)] = A[m][:] . W[n][:] + bi[n] + bh[n]
// perm: j = n&1023, gate = n>>10; idx = (j>>3)*32 + (j&7)*4 + gate
__global__ __launch_bounds__(256)
void gemm_xg(const float* __restrict__ A, const float* __restrict__ W,
             const float* __restrict__ bi, const float* __restrict__ bh,
             float* __restrict__ out)
{
    __shared__ float As[16][65];
    __shared__ float Bs[16][65];
    const int tid = threadIdx.x;
    const int m0 = blockIdx.y * 64, n0 = blockIdx.x * 64;
    const int tm = tid & 15, tn = tid >> 4;
    const int row = tid >> 2, q = tid & 3;
    float acc[4][4] = {{0.f}};
    for (int k0 = 0; k0 < HID; k0 += 16) {
        float4 a = *(const float4*)(A + (size_t)(m0 + row) * HID + k0 + q * 4);
        float4 b = *(const float4*)(W + (size_t)(n0 + row) * HID + k0 + q * 4);
        __syncthreads();
        As[q*4+0][row] = a.x; As[q*4+1][row] = a.y; As[q*4+2][row] = a.z; As[q*4+3][row] = a.w;
        Bs[q*4+0][row] = b.x; Bs[q*4+1][row] = b.y; Bs[q*4+2][row] = b.z; Bs[q*4+3][row] = b.w;
        __syncthreads();
#pragma unroll
        for (int kk = 0; kk < 16; ++kk) {
            float av[4], bv[4];
#pragma unroll
            for (int i = 0; i < 4; ++i) { av[i] = As[kk][tm*4+i]; bv[i] = Bs[kk][tn*4+i]; }
#pragma unroll
            for (int i = 0; i < 4; ++i)
#pragma unroll
                for (int j = 0; j < 4; ++j) acc[i][j] += av[i] * bv[j];
        }
    }
#pragma unroll
    for (int i = 0; i < 4; ++i) {
        int m = m0 + tm * 4 + i;
#pragma unroll
        for (int j = 0; j < 4; ++j) {
            int n = n0 + tn * 4 + j;
            float v = acc[i][j] + bi[n] + bh[n];
            int jd = n & (HID - 1), gate = n >> 10;
            out[(size_t)m * G4 + (jd >> 3) * 32 + (jd & 7) * 4 + gate] = v;
        }
    }
}

__device__ __forceinline__ void red4(float& a0, float& a1, float& a2, float& a3)
{
#pragma unroll
    for (int off = 32; off > 0; off >>= 1) {
        a0 += __shfl_xor(a0, off, 64);
        a1 += __shfl_xor(a1, off, 64);
        a2 += __shfl_xor(a2, off, 64);
        a3 += __shfl_xor(a3, off, 64);
    }
}

// Poll one 1024-dword slot with system-scope dwordx4 loads (fresh reads, no
// stale L2 service), per-group early-exit, mild sleep throttle. One wave
// covers the whole vector: lane reads 4 groups of 16B at [g*1024B + lane*16B].
__device__ __forceinline__ void poll_gather(const uint32* __restrict__ buf, uint32 tg,
                                            int lane, float* __restrict__ lds)
{
    const uint32* p = buf + lane * 4;
    uint4 v0, v1, v2, v3;
    unsigned done = 0;
    for (;;) {
        if (!(done & 1u)) asm volatile("global_load_dwordx4 %0, %1, off sc0 sc1"             : "=v"(v0) : "v"(p) : "memory");
        if (!(done & 2u)) asm volatile("global_load_dwordx4 %0, %1, off offset:1024 sc0 sc1" : "=v"(v1) : "v"(p) : "memory");
        if (!(done & 4u)) asm volatile("global_load_dwordx4 %0, %1, off offset:2048 sc0 sc1" : "=v"(v2) : "v"(p) : "memory");
        if (!(done & 8u)) asm volatile("global_load_dwordx4 %0, %1, off offset:3072 sc0 sc1" : "=v"(v3) : "v"(p) : "memory");
        asm volatile("s_waitcnt vmcnt(0)" ::: "memory");
        __builtin_amdgcn_sched_barrier(0);   // rule #18: keep checks after waitcnt
        if (!(done & 1u) && (v0.x & 15u) == tg && (v0.y & 15u) == tg &&
            (v0.z & 15u) == tg && (v0.w & 15u) == tg) done |= 1u;
        if (!(done & 2u) && (v1.x & 15u) == tg && (v1.y & 15u) == tg &&
            (v1.z & 15u) == tg && (v1.w & 15u) == tg) done |= 2u;
        if (!(done & 4u) && (v2.x & 15u) == tg && (v2.y & 15u) == tg &&
            (v2.z & 15u) == tg && (v2.w & 15u) == tg) done |= 4u;
        if (!(done & 8u) && (v3.x & 15u) == tg && (v3.y & 15u) == tg &&
            (v3.z & 15u) == tg && (v3.w & 15u) == tg) done |= 8u;
        if (__all(done == 15u)) break;
        __builtin_amdgcn_s_sleep(1);
    }
    union { uint4 u; float4 f; } c;
    c.u = v0; ((float4*)lds)[  0 + lane] = c.f;
    c.u = v1; ((float4*)lds)[ 64 + lane] = c.f;
    c.u = v2; ((float4*)lds)[128 + lane] = c.f;
    c.u = v3; ((float4*)lds)[192 + lane] = c.f;
}

// Merged 2-layer persistent LSTM. 128 blocks x 512 thr (8 waves), 1 block/CU.
// Wave w of block kb owns hidden unit j = 8*kb+w for BOTH layers; all weight
// rows live in VGPRs (whh0/whh1/wih1: 3 x 64 regs/thread). Layer 1 runs one
// step skewed behind layer 0 so each step needs only ONE publish->gather
// round trip on the critical (layer-0) chain:
//   iter t: L0 step t (uses hlA[p]=h0_{t-1}) -> publish h0_t
//           L1 step t-1 (uses hlA[p]=h0_{t-1}, hlB[p]=h1_{t-2}) -> publish h1_{t-1}
//           wave0 gathers h0_t -> hlA[p^1]; wave1 gathers h1_{t-1} -> hlB[p^1]
__global__ __launch_bounds__(NTHR)
void lstm_fused(const float* __restrict__ Whh0, const float* __restrict__ xg,
                const float* __restrict__ Wih1, const float* __restrict__ Whh1,
                const float* __restrict__ bih1, const float* __restrict__ bhh1,
                float* __restrict__ outF, Comm* __restrict__ cm)
{
    __shared__ float hlA[2][HID];
    __shared__ float hlB[2][HID];
    const int tid = threadIdx.x;
    const int wave = tid >> 6, lane = tid & 63;
    const int kb = blockIdx.x;
    const int j = 8 * kb + wave;

    float whh0[4][16], whh1[4][16], wih1[4][16];
#pragma unroll
    for (int g = 0; g < 4; ++g) {
        const float* p0 = Whh0 + (size_t)(g * HID + j) * HID + lane;
        const float* p1 = Whh1 + (size_t)(g * HID + j) * HID + lane;
        const float* p2 = Wih1 + (size_t)(g * HID + j) * HID + lane;
#pragma unroll
        for (int u = 0; u < 16; ++u) {
            whh0[g][u] = p0[u * 64];
            whh1[g][u] = p1[u * 64];
            wih1[g][u] = p2[u * 64];
        }
    }
    float bia[4];
#pragma unroll
    for (int g = 0; g < 4; ++g) bia[g] = bih1[g * HID + j] + bhh1[g * HID + j];

    for (int i = tid; i < HID; i += NTHR) {
        hlA[0][i] = 0.f; hlA[1][i] = 0.f; hlB[0][i] = 0.f; hlB[1][i] = 0.f;
    }

    float c0 = 0.f, c1 = 0.f;
    float nx0 = 0.f, nx1 = 0.f, nx2 = 0.f, nx3 = 0.f;
    if (lane == 0) {
        const float* xp = xg + kb * 32 + wave * 4;
        nx0 = xp[0]; nx1 = xp[1]; nx2 = xp[2]; nx3 = xp[3];
    }
    __syncthreads();

    for (int t = 0; t < T_STEPS; ++t) {
        const int p = t & 1;
        const float* hA = hlA[p];
        const float* hB = hlB[p];
        float x0 = nx0, x1 = nx1, x2 = nx2, x3 = nx3;
        if (lane == 0 && t + 1 < T_STEPS) {
            const float* xp = xg + (size_t)(t + 1) * G4 + kb * 32 + wave * 4;
            nx0 = xp[0]; nx1 = xp[1]; nx2 = xp[2]; nx3 = xp[3];
        }
        // ---- layer 0, step t (critical chain; publish ASAP) ----
        float a0 = 0.f, a1 = 0.f, a2 = 0.f, a3 = 0.f;
#pragma unroll
        for (int u = 0; u < 16; ++u) {
            float hv = hA[u * 64 + lane];
            a0 += whh0[0][u] * hv; a1 += whh0[1][u] * hv;
            a2 += whh0[2][u] * hv; a3 += whh0[3][u] * hv;
        }
        red4(a0, a1, a2, a3);
        if (lane == 0) {
            float ig = sigm(x0 + a0), fg = sigm(x1 + a1);
            float gg = tanh_f(x2 + a2), og = sigm(x3 + a3);
            c0 = fg * c0 + ig * gg;
            float h = og * tanh_f(c0);
            __hip_atomic_store(&cm->hA[t & 7][j], tagf(h, (t >> 3) & 15),
                               __ATOMIC_RELAXED, LD_AG);
        }
        // ---- layer 1, step t-1 (overlaps h0_t's flight) ----
        if (t >= 1) {
            float b0 = 0.f, b1 = 0.f, b2 = 0.f, b3 = 0.f;
#pragma unroll
            for (int u = 0; u < 16; ++u) {
                float h0v = hA[u * 64 + lane];
                float h1v = hB[u * 64 + lane];
                b0 += whh1[0][u] * h1v + wih1[0][u] * h0v;
                b1 += whh1[1][u] * h1v + wih1[1][u] * h0v;
                b2 += whh1[2][u] * h1v + wih1[2][u] * h0v;
                b3 += whh1[3][u] * h1v + wih1[3][u] * h0v;
            }
            red4(b0, b1, b2, b3);
            if (lane == 0) {
                float ig = sigm(bia[0] + b0), fg = sigm(bia[1] + b1);
                float gg = tanh_f(bia[2] + b2), og = sigm(bia[3] + b3);
                c1 = fg * c1 + ig * gg;
                float h = og * tanh_f(c1);
                __hip_atomic_store(&cm->hB[(t - 1) & 7][j],
                                   tagf(h, ((t - 1) >> 3) & 15),
                                   __ATOMIC_RELAXED, LD_AG);
            }
        }
        // ---- gather into the other parity buffers ----
        if (wave == 0) {
            poll_gather((const uint32*)cm->hA[t & 7], (uint32)((t >> 3) & 15),
                        lane, hlA[p ^ 1]);
        } else if (wave == 1 && t >= 1) {
            poll_gather((const uint32*)cm->hB[(t - 1) & 7],
                        (uint32)(((t - 1) >> 3) & 15), lane, hlB[p ^ 1]);
        }
        __syncthreads();
    }
    // ---- tail: layer 1, step T-1 -> final output ----
    {
        const float* hA = hlA[T_STEPS & 1];   // h0_{T-1}
        const float* hB = hlB[T_STEPS & 1];   // h1_{T-2}
        float b0 = 0.f, b1 = 0.f, b2 = 0.f, b3 = 0.f;
#pragma unroll
        for (int u = 0; u < 16; ++u) {
            float h0v = hA[u * 64 + lane];
            float h1v = hB[u * 64 + lane];
            b0 += whh1[0][u] * h1v + wih1[0][u] * h0v;
            b1 += whh1[1][u] * h1v + wih1[1][u] * h0v;
            b2 += whh1[2][u] * h1v + wih1[2][u] * h0v;
            b3 += whh1[3][u] * h1v + wih1[3][u] * h0v;
        }
        red4(b0, b1, b2, b3);
        if (lane == 0) {
            float ig = sigm(bia[0] + b0), fg = sigm(bia[1] + b1);
            float gg = tanh_f(bia[2] + b2), og = sigm(bia[3] + b3);
            c1 = fg * c1 + ig * gg;
            outF[j] = og * tanh_f(c1);
        }
    }
}

extern "C" void kernel_launch(void* const* d_in, const int* in_sizes, int n_in,
                              void* d_out, int out_size, void* d_ws, size_t ws_size,
                              hipStream_t stream)
{
    const float* x    = (const float*)d_in[0];
    const float* Wih0 = (const float*)d_in[1];
    const float* Whh0 = (const float*)d_in[2];
    const float* bih0 = (const float*)d_in[3];
    const float* bhh0 = (const float*)d_in[4];
    const float* Wih1 = (const float*)d_in[5];
    const float* Whh1 = (const float*)d_in[6];
    const float* bih1 = (const float*)d_in[7];
    const float* bhh1 = (const float*)d_in[8];

    char* ws = (char*)d_ws;
    float* xg = (float*)ws;                     // 134217728 B
    Comm*  cm = (Comm*)(ws + 134217728);        // 65536 B

    // 0xFF fill: tag = 15; slot s only expects tag 15 at t = s + 120, by which
    // point the slot has been rewritten 15 times — init pattern long gone.
    (void)hipMemsetAsync(ws + 134217728, 0xFF, sizeof(Comm), stream);

    dim3 gg(G4 / 64, T_STEPS / 64);
    gemm_xg<<<gg, 256, 0, stream>>>(x, Wih0, bih0, bhh0, xg);
    lstm_fused<<<NBLK, NTHR, 0, stream>>>(Whh0, xg, Wih1, Whh1, bih1, bhh1,
                                          (float*)d_out, cm);
}